// Round 12
// baseline (1117.845 us; speedup 1.0000x reference)
//
#include <hip/hip_runtime.h>
#include <math.h>

#define TT 256
#define HH 100
#define GG 400
#define BB 512

// ---- DPP quad-perm helpers (4-lane groups; VALU pipe) ----------------------
#define DPP_ROT1 147   // dest l <- src (l-1)&3 : perm [3,0,1,2]
#define DPP_ROT2 78    // dest l <- src (l-2)&3 : perm [2,3,0,1]
#define DPP_ROT3 57    // dest l <- src (l-3)&3 : perm [1,2,3,0]
#define DPP_XOR1 177   // perm [1,0,3,2]
#define DPP_XOR2 78    // perm [2,3,0,1]
#define DPP_XOR3 27    // perm [3,2,1,0]

template<int CTRL>
__device__ __forceinline__ float dppf(float v) {
    int i = __float_as_int(v);
    int r = __builtin_amdgcn_update_dpp(i, i, CTRL, 0xf, 0xf, false);
    return __int_as_float(r);
}

// raw transcendental ops (1-ulp class; avoids IEEE div expansion)
__device__ __forceinline__ float fexp2(float x) {
    float r; asm("v_exp_f32 %0, %1" : "=v"(r) : "v"(x)); return r;
}
__device__ __forceinline__ float frcp(float x) {
    float r; asm("v_rcp_f32 %0, %1" : "=v"(r) : "v"(x)); return r;
}
#define LOG2E 1.44269504088896f

// LDS-drain-only barrier: keeps global loads/stores in flight
__device__ __forceinline__ void bar_lds() {
    asm volatile("s_waitcnt lgkmcnt(0)" ::: "memory");
    __builtin_amdgcn_s_barrier();
    asm volatile("" ::: "memory");
}

// ============================ recurrence kernel ==============================
// 256 blocks x 512 threads, TWO batch rows per block, 1 block/CU.
// amdgpu_waves_per_eu(2,2): pins target occupancy to exactly 2 waves/EU
// (= this one block) -> allocator has the full 256-reg budget and NO
// incentive to bank the 100-float Wq into AGPRs (every lb(...,N>=3) compile
// banked it -> 2x VALU-issue inflation, R4-R11).
// Thread (u=tid>>2, ty=tid&3): k-quarter [25ty,25ty+25) partials for gates
// {((ty+d)&3)*100+u}, BOTH rows (Wq shared). DPP-rotate combine (R4-verified).
// Tail: ty0 lane updates row0 state, ty1 lane row1.
template<int LK>
__global__ void __launch_bounds__(512)
__attribute__((amdgpu_waves_per_eu(2, 2)))
lstm_recur(const float* __restrict__ x,        // [B][T][2]   (LK==0)
           const float* __restrict__ pre,      // [T*B][400]  (LK>=1, bias folded)
           const float* __restrict__ Whh,      // [400][100]
           const float* __restrict__ Wih0,     // [400][2]    (LK==0)
           const float* __restrict__ bih,      // [400]       (LK==0)
           const float* __restrict__ bhh,      // [400]       (LK==0)
           const float* __restrict__ head_w,   // [100]
           const float* __restrict__ head_b,   // [1]
           float* __restrict__ hs,             // [B][T][100] (LK<2 out)
           float* __restrict__ out)            // [B]         (LK==2 out)
{
    __shared__ float hbuf[2][2][4][28];  // [buf][row][quarter][25 used + 3 pad]

    const int tid = threadIdx.x;
    const int b0  = blockIdx.x * 2;
    const int u   = tid >> 2, ty = tid & 3;
    const int g   = ty * HH + u;         // own gate row
    const bool on = (tid < GG);

    // Wq[d][k] = Whh[((ty+d)&3)*100 + u][25*ty + k]
    float Wq[4][25];
    float w0a = 0.f, w0b = 0.f, bias = 0.f;
    if (on) {
        #pragma unroll
        for (int d = 0; d < 4; ++d) {
            const float* wrow = Whh + (((ty + d) & 3) * HH + u) * HH + 25 * ty;
            #pragma unroll
            for (int k = 0; k < 25; ++k) Wq[d][k] = wrow[k];
        }
        if (LK == 0) {
            w0a = Wih0[2 * g]; w0b = Wih0[2 * g + 1];
            bias = bih[g] + bhh[g];
        }
    }
    if (tid < 448) (&hbuf[0][0][0][0])[tid] = 0.f;   // zero both bufs + pads
    float c = 0.f;                       // ty0: row0 cell; ty1: row1 cell
    const int q_w = u / 25, i_w = u % 25;
    __syncthreads();

    // prefetch t=0 inputs
    float p0 = 0.f, p1 = 0.f;
    float2 xa = {0.f, 0.f}, xb = {0.f, 0.f};
    if (on) {
        if (LK == 0) {
            xa = *(const float2*)(x + (size_t)(b0    ) * TT * 2);
            xb = *(const float2*)(x + (size_t)(b0 + 1) * TT * 2);
        } else {
            p0 = pre[((size_t)0 * BB + b0    ) * GG + g];
            p1 = pre[((size_t)0 * BB + b0 + 1) * GG + g];
        }
    }

    for (int t = 0; t < TT; ++t) {
        const int cur = t & 1, nxt = cur ^ 1;
        if (on) {
            float ext0, ext1;
            if (LK == 0) {
                ext0 = bias + w0a * xa.x + w0b * xa.y;
                ext1 = bias + w0a * xb.x + w0b * xb.y;
            } else {
                ext0 = p0; ext1 = p1;
            }
            // prefetch t+1 (stays in flight across the raw barrier)
            const int tn = (t + 1 < TT) ? t + 1 : t;
            if (LK == 0) {
                xa = *(const float2*)(x + ((size_t)(b0    ) * TT + tn) * 2);
                xb = *(const float2*)(x + ((size_t)(b0 + 1) * TT + tn) * 2);
            } else {
                p0 = pre[((size_t)tn * BB + b0    ) * GG + g];
                p1 = pre[((size_t)tn * BB + b0 + 1) * GG + g];
            }

            float sr[2];
            #pragma unroll
            for (int r = 0; r < 2; ++r) {
                const float4* hq = (const float4*)&hbuf[cur][r][ty][0];
                float pA = 0.f, pB = 0.f, pC = 0.f, pD = 0.f;
                #pragma unroll
                for (int i = 0; i < 6; ++i) {
                    const float4 h4 = hq[i];
                    pA += Wq[0][4*i+0] * h4.x; pB += Wq[1][4*i+0] * h4.x;
                    pC += Wq[2][4*i+0] * h4.x; pD += Wq[3][4*i+0] * h4.x;
                    pA += Wq[0][4*i+1] * h4.y; pB += Wq[1][4*i+1] * h4.y;
                    pC += Wq[2][4*i+1] * h4.y; pD += Wq[3][4*i+1] * h4.y;
                    pA += Wq[0][4*i+2] * h4.z; pB += Wq[1][4*i+2] * h4.z;
                    pC += Wq[2][4*i+2] * h4.z; pD += Wq[3][4*i+2] * h4.z;
                    pA += Wq[0][4*i+3] * h4.w; pB += Wq[1][4*i+3] * h4.w;
                    pC += Wq[2][4*i+3] * h4.w; pD += Wq[3][4*i+3] * h4.w;
                }
                const float hl = hq[6].x;   // k = 24 of the quarter
                pA += Wq[0][24] * hl; pB += Wq[1][24] * hl;
                pC += Wq[2][24] * hl; pD += Wq[3][24] * hl;

                // lane j accumulates gate-j partials from lanes j-1, j-2, j-3
                float tot = pA + dppf<DPP_ROT1>(pB) + dppf<DPP_ROT2>(pC)
                               + dppf<DPP_ROT3>(pD) + (r == 0 ? ext0 : ext1);

                // activation by own role (ty==2 is the g-gate -> tanh)
                const bool isG = (ty == 2);
                float v = isG ? 2.f * tot : tot;
                float s = frcp(1.f + fexp2(-LOG2E * v));
                if (isG) s = 2.f * s - 1.f;
                sr[r] = s;
            }

            // gather gates: lane l, XORk -> activated gate l^k (of that row)
            const float s0 = sr[0], s1 = sr[1];
            float X10 = dppf<DPP_XOR1>(s0), X20 = dppf<DPP_XOR2>(s0), X30 = dppf<DPP_XOR3>(s0);
            float X11 = dppf<DPP_XOR1>(s1), X21 = dppf<DPP_XOR2>(s1), X31 = dppf<DPP_XOR3>(s1);

            if (ty == 0) {          // row0: own=i, X1=f, X2=g, X3=o
                c = X10 * c + s0 * X20;
                float th = 2.f * frcp(1.f + fexp2(-2.f * LOG2E * c)) - 1.f;
                float hv = X30 * th;
                hbuf[nxt][0][q_w][i_w] = hv;
                if (LK < 2) hs[((size_t)(b0    ) * TT + t) * HH + u] = hv;
            } else if (ty == 1) {   // row1: own=f, X1=i, X2=o, X3=g
                c = s1 * c + X11 * X31;
                float th = 2.f * frcp(1.f + fexp2(-2.f * LOG2E * c)) - 1.f;
                float hv = X21 * th;
                hbuf[nxt][1][q_w][i_w] = hv;
                if (LK < 2) hs[((size_t)(b0 + 1) * TT + t) * HH + u] = hv;
            }
        }
        bar_lds();   // h(t) visible; orders hbuf[cur] reuse at t+1
    }

    // head: final h is in hbuf[0] (t=255 wrote nxt=0)
    if (LK == 2 && tid < 128) {
        const int lane = tid & 63, wv = tid >> 6;
        float p = hbuf[0][wv][lane / 25][lane % 25] * head_w[lane];
        if (lane < 36) {
            const int k2 = 64 + lane;
            p += hbuf[0][wv][k2 / 25][k2 % 25] * head_w[k2];
        }
        #pragma unroll
        for (int off = 32; off; off >>= 1) p += __shfl_down(p, off);
        if (lane == 0) out[b0 + wv] = p + head_b[0];
    }
}

// ============================ x-projection GEMM ==============================
// (unchanged from R11 — ~135 us each) 8x8-fragment tiled GEMM, LDS-BW bound.
__global__ void __launch_bounds__(400, 1)
gemm_pre(const float* __restrict__ hs,     // [B][T][100]
         const float* __restrict__ Wih,    // [400][100]
         const float* __restrict__ bih,    // [400]
         const float* __restrict__ bhh,    // [400]
         float* __restrict__ pre)          // [M][400]
{
    extern __shared__ float lds[];
    float* A_s = lds;            // [100][128]  12800 floats
    float* W_s = lds + 12800;    // [100][200]  20000 floats

    const int tid = threadIdx.x;           // 400
    const int ti  = tid / 25;              // 0..15 -> rows 8ti..8ti+7
    const int tj  = tid % 25;              // 0..24 -> gates 8tj..8tj+7
    const int row0   = blockIdx.x * 128;   // same t (512%128==0)
    const int t      = row0 >> 9;
    const int b_base = row0 & 511;
    const int gbase  = blockIdx.y * 200;

    #pragma unroll
    for (int s = 0; s < 8; ++s) {
        const int L  = tid + 400 * s;      // 0..3199
        const int r  = L / 25, kq = L % 25;
        float4 v = *(const float4*)(hs + ((size_t)(b_base + r) * TT + t) * HH + 4 * kq);
        const int ph = r ^ ((kq & 7) << 3);
        A_s[(4*kq+0)*128 + ph] = v.x;
        A_s[(4*kq+1)*128 + ph] = v.y;
        A_s[(4*kq+2)*128 + ph] = v.z;
        A_s[(4*kq+3)*128 + ph] = v.w;
    }
    for (int L = tid; L < 5000; L += 400) {
        const int kq = L / 200, gl = L % 200;
        float4 v = *(const float4*)(Wih + (size_t)(gbase + gl) * HH + 4 * kq);
        W_s[(4*kq+0)*200 + gl] = v.x;
        W_s[(4*kq+1)*200 + gl] = v.y;
        W_s[(4*kq+2)*200 + gl] = v.z;
        W_s[(4*kq+3)*200 + gl] = v.w;
    }
    __syncthreads();

    float bj[8];
    {
        const float4 a1 = *(const float4*)(bih + gbase + 8 * tj);
        const float4 a2 = *(const float4*)(bih + gbase + 8 * tj + 4);
        const float4 c1 = *(const float4*)(bhh + gbase + 8 * tj);
        const float4 c2 = *(const float4*)(bhh + gbase + 8 * tj + 4);
        bj[0] = a1.x + c1.x; bj[1] = a1.y + c1.y; bj[2] = a1.z + c1.z; bj[3] = a1.w + c1.w;
        bj[4] = a2.x + c2.x; bj[5] = a2.y + c2.y; bj[6] = a2.z + c2.z; bj[7] = a2.w + c2.w;
    }
    float acc[8][8];
    #pragma unroll
    for (int i = 0; i < 8; ++i)
        #pragma unroll
        for (int j = 0; j < 8; ++j) acc[i][j] = bj[j];

    for (int kq = 0; kq < 25; ++kq) {
        const int axo = (8 * ti) ^ ((kq & 7) << 3);
        #pragma unroll
        for (int e = 0; e < 4; ++e) {
            const float* Ak = &A_s[(4*kq + e) * 128];
            const float* Wk = &W_s[(4*kq + e) * 200];
            const float4 a0 = *(const float4*)(Ak + axo);
            const float4 a1 = *(const float4*)(Ak + axo + 4);
            const float4 w0 = *(const float4*)(Wk + 8 * tj);
            const float4 w1 = *(const float4*)(Wk + 8 * tj + 4);
            const float av[8] = {a0.x, a0.y, a0.z, a0.w, a1.x, a1.y, a1.z, a1.w};
            const float wv[8] = {w0.x, w0.y, w0.z, w0.w, w1.x, w1.y, w1.z, w1.w};
            #pragma unroll
            for (int i = 0; i < 8; ++i)
                #pragma unroll
                for (int j = 0; j < 8; ++j)
                    acc[i][j] += av[i] * wv[j];
        }
    }

    #pragma unroll
    for (int i = 0; i < 8; ++i) {
        const size_t row = (size_t)row0 + 8 * ti + i;
        float4 o0, o1;
        o0.x = acc[i][0]; o0.y = acc[i][1]; o0.z = acc[i][2]; o0.w = acc[i][3];
        o1.x = acc[i][4]; o1.y = acc[i][5]; o1.z = acc[i][6]; o1.w = acc[i][7];
        *(float4*)(pre + row * GG + gbase + 8 * tj)     = o0;
        *(float4*)(pre + row * GG + gbase + 8 * tj + 4) = o1;
    }
}

// =============================================================================
extern "C" void kernel_launch(void* const* d_in, const int* in_sizes, int n_in,
                              void* d_out, int out_size, void* d_ws, size_t ws_size,
                              hipStream_t stream) {
    const float* x         = (const float*)d_in[0];
    const float* W_ih0     = (const float*)d_in[1];
    const float* W_ih_rest = (const float*)d_in[2];
    const float* W_hh      = (const float*)d_in[3];
    const float* b_ih      = (const float*)d_in[4];
    const float* b_hh      = (const float*)d_in[5];
    const float* head_w    = (const float*)d_in[6];
    const float* head_b    = (const float*)d_in[7];
    float* out = (float*)d_out;

    const size_t HS_BYTES = (size_t)BB * TT * HH * 4;   // 52.4 MB
    float* hs  = (float*)d_ws;
    float* pre = (float*)((char*)d_ws + HS_BYTES);      // 209.7 MB

    const int gemm_lds = (12800 + 20000) * 4;           // 131,200 B
    hipFuncSetAttribute((const void*)gemm_pre,
                        hipFuncAttributeMaxDynamicSharedMemorySize, gemm_lds);
    dim3 ggrid(1024, 2);

    lstm_recur<0><<<256, 512, 0, stream>>>(
        x, nullptr, W_hh, W_ih0, b_ih, b_hh, head_w, head_b, hs, out);

    gemm_pre<<<ggrid, 400, gemm_lds, stream>>>(hs, W_ih_rest, b_ih + GG, b_hh + GG, pre);
    lstm_recur<1><<<256, 512, 0, stream>>>(
        nullptr, pre, W_hh + 40000, nullptr, nullptr, nullptr, head_w, head_b, hs, out);

    gemm_pre<<<ggrid, 400, gemm_lds, stream>>>(hs, W_ih_rest + 40000, b_ih + 2*GG, b_hh + 2*GG, pre);
    lstm_recur<2><<<256, 512, 0, stream>>>(
        nullptr, pre, W_hh + 80000, nullptr, nullptr, nullptr, head_w, head_b, hs, out);
}

// Round 13
// 1060.419 us; speedup vs baseline: 1.0542x; 1.0542x over previous
//
#include <hip/hip_runtime.h>
#include <math.h>

#define TT 256
#define HH 100
#define GG 400
#define BB 512

// ---- DPP quad-perm helpers (4-lane groups; VALU pipe) ----------------------
#define DPP_ROT1 147   // dest l <- src (l-1)&3 : perm [3,0,1,2]
#define DPP_ROT2 78    // dest l <- src (l-2)&3 : perm [2,3,0,1]
#define DPP_ROT3 57    // dest l <- src (l-3)&3 : perm [1,2,3,0]
#define DPP_XOR1 177   // perm [1,0,3,2]
#define DPP_XOR2 78    // perm [2,3,0,1]
#define DPP_XOR3 27    // perm [3,2,1,0]

template<int CTRL>
__device__ __forceinline__ float dppf(float v) {
    int i = __float_as_int(v);
    int r = __builtin_amdgcn_update_dpp(i, i, CTRL, 0xf, 0xf, false);
    return __int_as_float(r);
}

// raw transcendental ops (1-ulp class; avoids IEEE div expansion)
__device__ __forceinline__ float fexp2(float x) {
    float r; asm("v_exp_f32 %0, %1" : "=v"(r) : "v"(x)); return r;
}
__device__ __forceinline__ float frcp(float x) {
    float r; asm("v_rcp_f32 %0, %1" : "=v"(r) : "v"(x)); return r;
}
#define LOG2E 1.44269504088896f

// LDS-drain-only barrier: keeps global loads/stores in flight
__device__ __forceinline__ void bar_lds() {
    asm volatile("s_waitcnt lgkmcnt(0)" ::: "memory");
    __builtin_amdgcn_s_barrier();
    asm volatile("" ::: "memory");
}

// Zero-instruction arch-VGPR pin: forces each value to live in an arch VGPR
// at this point. Every recur compile so far banked the 100-float Wq into
// AGPRs (v_accvgpr_read per use = the measured ~2x VALU-issue inflation);
// pinning each element every iteration makes "keep it in a VGPR" the
// allocator's copy-minimal assignment. Empty asm -> no encoding risk.
#define PIN25(A)                                                            \
    asm volatile("" : "+v"(A[0]), "+v"(A[1]), "+v"(A[2]), "+v"(A[3]),       \
                      "+v"(A[4]), "+v"(A[5]), "+v"(A[6]), "+v"(A[7]),       \
                      "+v"(A[8]), "+v"(A[9]), "+v"(A[10]), "+v"(A[11]),     \
                      "+v"(A[12]), "+v"(A[13]), "+v"(A[14]), "+v"(A[15]),   \
                      "+v"(A[16]), "+v"(A[17]), "+v"(A[18]), "+v"(A[19]),   \
                      "+v"(A[20]), "+v"(A[21]), "+v"(A[22]), "+v"(A[23]),   \
                      "+v"(A[24]))

// ============================ recurrence kernel ==============================
// R8 structure (best measured: ~180 us/layer): 512 blocks x 448 threads,
// 1 batch row/block; lb(448,3) cap 170. Thread (u=tid>>2, ty=tid&3):
// k-quarter [25ty,25ty+25) partials for gates {((ty+d)&3)*100+u};
// DPP-rotate combine (R4-verified). h double-buffered in LDS [2][4][28].
// NEW: per-iteration VGPR pins on Wq (see PIN25).
template<int LK>
__global__ void __launch_bounds__(448, 3)
lstm_recur(const float* __restrict__ x,        // [B][T][2]   (LK==0)
           const float* __restrict__ pre,      // [T*B][400]  (LK>=1, bias folded)
           const float* __restrict__ Whh,      // [400][100]
           const float* __restrict__ Wih0,     // [400][2]    (LK==0)
           const float* __restrict__ bih,      // [400]       (LK==0)
           const float* __restrict__ bhh,      // [400]       (LK==0)
           const float* __restrict__ head_w,   // [100]
           const float* __restrict__ head_b,   // [1]
           float* __restrict__ hs,             // [B][T][100] (LK<2 out)
           float* __restrict__ out)            // [B]         (LK==2 out)
{
    __shared__ float hbuf[2][4][28];   // [buf][quarter][25 used + 3 pad]

    const int tid = threadIdx.x;
    const int b   = blockIdx.x;        // one batch row per block
    const int u   = tid >> 2, ty = tid & 3;
    const int g   = ty * HH + u;       // own gate row
    const bool on = (tid < GG);

    // Wq[d][k] = Whh[((ty+d)&3)*100 + u][25*ty + k]
    float Wq[4][25];
    float w0a = 0.f, w0b = 0.f, bias = 0.f;
    if (on) {
        #pragma unroll
        for (int d = 0; d < 4; ++d) {
            const float* wrow = Whh + (((ty + d) & 3) * HH + u) * HH + 25 * ty;
            #pragma unroll
            for (int k = 0; k < 25; ++k) Wq[d][k] = wrow[k];
        }
        if (LK == 0) {
            w0a = Wih0[2 * g]; w0b = Wih0[2 * g + 1];
            bias = bih[g] + bhh[g];
        }
    }
    if (tid < 224) (&hbuf[0][0][0])[tid] = 0.f;   // zero both bufs incl. pads
    float c = 0.f;                                // ty==0 lanes own unit u's cell
    const int q_w = u / 25, i_w = u % 25;         // writer position
    __syncthreads();

    // prefetch t=0 input
    float p0 = 0.f;
    float2 xa = {0.f, 0.f};
    if (on) {
        if (LK == 0) xa = *(const float2*)(x + (size_t)b * TT * 2);
        else         p0 = pre[((size_t)0 * BB + b) * GG + g];
    }

    for (int t = 0; t < TT; ++t) {
        const int cur = t & 1, nxt = cur ^ 1;
        if (on) {
            // keep the weight array in ARCH VGPRs for this iteration
            PIN25(Wq[0]); PIN25(Wq[1]); PIN25(Wq[2]); PIN25(Wq[3]);

            float ext;
            if (LK == 0) ext = bias + w0a * xa.x + w0b * xa.y;
            else         ext = p0;

            // prefetch t+1 (stays in flight across the raw barrier)
            const int tn = (t + 1 < TT) ? t + 1 : t;
            if (LK == 0) xa = *(const float2*)(x + ((size_t)b * TT + tn) * 2);
            else         p0 = pre[((size_t)tn * BB + b) * GG + g];

            const float4* hq = (const float4*)&hbuf[cur][ty][0];

            float pA = 0.f, pB = 0.f, pC = 0.f, pD = 0.f;
            #pragma unroll
            for (int i = 0; i < 6; ++i) {
                const float4 h4 = hq[i];
                pA += Wq[0][4*i+0] * h4.x; pB += Wq[1][4*i+0] * h4.x;
                pC += Wq[2][4*i+0] * h4.x; pD += Wq[3][4*i+0] * h4.x;
                pA += Wq[0][4*i+1] * h4.y; pB += Wq[1][4*i+1] * h4.y;
                pC += Wq[2][4*i+1] * h4.y; pD += Wq[3][4*i+1] * h4.y;
                pA += Wq[0][4*i+2] * h4.z; pB += Wq[1][4*i+2] * h4.z;
                pC += Wq[2][4*i+2] * h4.z; pD += Wq[3][4*i+2] * h4.z;
                pA += Wq[0][4*i+3] * h4.w; pB += Wq[1][4*i+3] * h4.w;
                pC += Wq[2][4*i+3] * h4.w; pD += Wq[3][4*i+3] * h4.w;
            }
            const float hl = hq[6].x;   // k = 24 of the quarter
            pA += Wq[0][24] * hl; pB += Wq[1][24] * hl;
            pC += Wq[2][24] * hl; pD += Wq[3][24] * hl;

            // cross-quad combine: lane j gets gate-j partials from j-1,j-2,j-3
            float tot = pA + dppf<DPP_ROT1>(pB) + dppf<DPP_ROT2>(pC)
                           + dppf<DPP_ROT3>(pD) + ext;

            // activation by own role (ty==2 is the g-gate -> tanh)
            const bool isG = (ty == 2);
            float v = isG ? 2.f * tot : tot;
            float s = frcp(1.f + fexp2(-LOG2E * v));
            if (isG) s = 2.f * s - 1.f;

            // gather the other three activated gates
            float B0 = dppf<DPP_XOR1>(s), C0 = dppf<DPP_XOR2>(s), D0 = dppf<DPP_XOR3>(s);

            if (ty == 0) {   // s=sig(i), B0=sig(f), C0=tanh(g), D0=sig(o)
                c = B0 * c + s * C0;
                float th = 2.f * frcp(1.f + fexp2(-2.f * LOG2E * c)) - 1.f;
                float hv = D0 * th;
                hbuf[nxt][q_w][i_w] = hv;
                if (LK < 2) hs[((size_t)b * TT + t) * HH + u] = hv;
            }
        }
        bar_lds();   // h(t) visible; orders hbuf[cur] reuse at t+1
    }

    // head: final h is in hbuf[0] (t=255 wrote nxt=0)
    if (LK == 2 && tid < 64) {
        const int lane = tid;
        float p = hbuf[0][lane / 25][lane % 25] * head_w[lane];
        if (lane < 36) {
            const int k2 = 64 + lane;
            p += hbuf[0][k2 / 25][k2 % 25] * head_w[k2];
        }
        #pragma unroll
        for (int off = 32; off; off >>= 1) p += __shfl_down(p, off);
        if (lane == 0) out[b] = p + head_b[0];
    }
}

// ============================ x-projection GEMM ==============================
// (unchanged from R11 — ~135 us each) 8x8-fragment tiled GEMM, LDS-BW bound.
__global__ void __launch_bounds__(400, 1)
gemm_pre(const float* __restrict__ hs,     // [B][T][100]
         const float* __restrict__ Wih,    // [400][100]
         const float* __restrict__ bih,    // [400]
         const float* __restrict__ bhh,    // [400]
         float* __restrict__ pre)          // [M][400]
{
    extern __shared__ float lds[];
    float* A_s = lds;            // [100][128]  12800 floats
    float* W_s = lds + 12800;    // [100][200]  20000 floats

    const int tid = threadIdx.x;           // 400
    const int ti  = tid / 25;              // 0..15 -> rows 8ti..8ti+7
    const int tj  = tid % 25;              // 0..24 -> gates 8tj..8tj+7
    const int row0   = blockIdx.x * 128;   // same t (512%128==0)
    const int t      = row0 >> 9;
    const int b_base = row0 & 511;
    const int gbase  = blockIdx.y * 200;

    #pragma unroll
    for (int s = 0; s < 8; ++s) {
        const int L  = tid + 400 * s;      // 0..3199
        const int r  = L / 25, kq = L % 25;
        float4 v = *(const float4*)(hs + ((size_t)(b_base + r) * TT + t) * HH + 4 * kq);
        const int ph = r ^ ((kq & 7) << 3);
        A_s[(4*kq+0)*128 + ph] = v.x;
        A_s[(4*kq+1)*128 + ph] = v.y;
        A_s[(4*kq+2)*128 + ph] = v.z;
        A_s[(4*kq+3)*128 + ph] = v.w;
    }
    for (int L = tid; L < 5000; L += 400) {
        const int kq = L / 200, gl = L % 200;
        float4 v = *(const float4*)(Wih + (size_t)(gbase + gl) * HH + 4 * kq);
        W_s[(4*kq+0)*200 + gl] = v.x;
        W_s[(4*kq+1)*200 + gl] = v.y;
        W_s[(4*kq+2)*200 + gl] = v.z;
        W_s[(4*kq+3)*200 + gl] = v.w;
    }
    __syncthreads();

    float bj[8];
    {
        const float4 a1 = *(const float4*)(bih + gbase + 8 * tj);
        const float4 a2 = *(const float4*)(bih + gbase + 8 * tj + 4);
        const float4 c1 = *(const float4*)(bhh + gbase + 8 * tj);
        const float4 c2 = *(const float4*)(bhh + gbase + 8 * tj + 4);
        bj[0] = a1.x + c1.x; bj[1] = a1.y + c1.y; bj[2] = a1.z + c1.z; bj[3] = a1.w + c1.w;
        bj[4] = a2.x + c2.x; bj[5] = a2.y + c2.y; bj[6] = a2.z + c2.z; bj[7] = a2.w + c2.w;
    }
    float acc[8][8];
    #pragma unroll
    for (int i = 0; i < 8; ++i)
        #pragma unroll
        for (int j = 0; j < 8; ++j) acc[i][j] = bj[j];

    for (int kq = 0; kq < 25; ++kq) {
        const int axo = (8 * ti) ^ ((kq & 7) << 3);
        #pragma unroll
        for (int e = 0; e < 4; ++e) {
            const float* Ak = &A_s[(4*kq + e) * 128];
            const float* Wk = &W_s[(4*kq + e) * 200];
            const float4 a0 = *(const float4*)(Ak + axo);
            const float4 a1 = *(const float4*)(Ak + axo + 4);
            const float4 w0 = *(const float4*)(Wk + 8 * tj);
            const float4 w1 = *(const float4*)(Wk + 8 * tj + 4);
            const float av[8] = {a0.x, a0.y, a0.z, a0.w, a1.x, a1.y, a1.z, a1.w};
            const float wv[8] = {w0.x, w0.y, w0.z, w0.w, w1.x, w1.y, w1.z, w1.w};
            #pragma unroll
            for (int i = 0; i < 8; ++i)
                #pragma unroll
                for (int j = 0; j < 8; ++j)
                    acc[i][j] += av[i] * wv[j];
        }
    }

    #pragma unroll
    for (int i = 0; i < 8; ++i) {
        const size_t row = (size_t)row0 + 8 * ti + i;
        float4 o0, o1;
        o0.x = acc[i][0]; o0.y = acc[i][1]; o0.z = acc[i][2]; o0.w = acc[i][3];
        o1.x = acc[i][4]; o1.y = acc[i][5]; o1.z = acc[i][6]; o1.w = acc[i][7];
        *(float4*)(pre + row * GG + gbase + 8 * tj)     = o0;
        *(float4*)(pre + row * GG + gbase + 8 * tj + 4) = o1;
    }
}

// =============================================================================
extern "C" void kernel_launch(void* const* d_in, const int* in_sizes, int n_in,
                              void* d_out, int out_size, void* d_ws, size_t ws_size,
                              hipStream_t stream) {
    const float* x         = (const float*)d_in[0];
    const float* W_ih0     = (const float*)d_in[1];
    const float* W_ih_rest = (const float*)d_in[2];
    const float* W_hh      = (const float*)d_in[3];
    const float* b_ih      = (const float*)d_in[4];
    const float* b_hh      = (const float*)d_in[5];
    const float* head_w    = (const float*)d_in[6];
    const float* head_b    = (const float*)d_in[7];
    float* out = (float*)d_out;

    const size_t HS_BYTES = (size_t)BB * TT * HH * 4;   // 52.4 MB
    float* hs  = (float*)d_ws;
    float* pre = (float*)((char*)d_ws + HS_BYTES);      // 209.7 MB

    const int gemm_lds = (12800 + 20000) * 4;           // 131,200 B
    hipFuncSetAttribute((const void*)gemm_pre,
                        hipFuncAttributeMaxDynamicSharedMemorySize, gemm_lds);
    dim3 ggrid(1024, 2);

    lstm_recur<0><<<512, 448, 0, stream>>>(
        x, nullptr, W_hh, W_ih0, b_ih, b_hh, head_w, head_b, hs, out);

    gemm_pre<<<ggrid, 400, gemm_lds, stream>>>(hs, W_ih_rest, b_ih + GG, b_hh + GG, pre);
    lstm_recur<1><<<512, 448, 0, stream>>>(
        nullptr, pre, W_hh + 40000, nullptr, nullptr, nullptr, head_w, head_b, hs, out);

    gemm_pre<<<ggrid, 400, gemm_lds, stream>>>(hs, W_ih_rest + 40000, b_ih + 2*GG, b_hh + 2*GG, pre);
    lstm_recur<2><<<512, 448, 0, stream>>>(
        nullptr, pre, W_hh + 80000, nullptr, nullptr, nullptr, head_w, head_b, hs, out);
}